// Round 10
// baseline (225.738 us; speedup 1.0000x reference)
//
#include <hip/hip_runtime.h>
#include <stdint.h>
#include <stddef.h>

typedef __bf16 bf16_t;
typedef __bf16 bf16x8 __attribute__((ext_vector_type(8)));
typedef __bf16 bf16x4 __attribute__((ext_vector_type(4)));
typedef float f32x4 __attribute__((ext_vector_type(4)));

#define VMW(n) asm volatile("s_waitcnt vmcnt(" #n ")" ::: "memory")
#define LGKM0 asm volatile("s_waitcnt lgkmcnt(0)" ::: "memory")
#define CFENCE asm volatile("" ::: "memory")
#define RAWBAR              \
  do {                      \
    __builtin_amdgcn_s_barrier(); \
    CFENCE;                 \
  } while (0)

__device__ __forceinline__ void gload_lds16(const void* g, void* l) {
  __builtin_amdgcn_global_load_lds(
      (const __attribute__((address_space(1))) uint32_t*)g,
      (__attribute__((address_space(3))) uint32_t*)l, 16, 0, 0);
}

// ---------------- w2s: w2s[r*256+m] = sum_n w2[((r*256+m)*64)+n] ----------------
__global__ __launch_bounds__(256) void w2s_k(const float* __restrict__ w2,
                                             float* __restrict__ w2s) {
  const int r = blockIdx.x, m = threadIdx.x;
  const float4* p = (const float4*)(w2 + ((size_t)(r * 256 + m)) * 64);
  float s = 0.f;
#pragma unroll
  for (int i = 0; i < 16; ++i) {
    float4 v = p[i];
    s += (v.x + v.y) + (v.z + v.w);
  }
  w2s[r * 256 + m] = s;
}

// ---------------- merged prep ----------------
// blocks 0..255:   w1t[m*4096+k] = bf16(w1[k*256+m] * w2s[(k&63)*256+m])
// blocks 256..511: w3pt[(o*64+r)*256+m] = bf16(w3[m*4096 + r*64 + o])
// block 512:       c2[m] = sum_r bias1[r]*w2s[r*256+m] + 64*bias2[m]
__global__ __launch_bounds__(256) void prep_k(
    const float* __restrict__ w1, const float* __restrict__ w3,
    const float* __restrict__ w2s, const float* __restrict__ bias1,
    const float* __restrict__ bias2, bf16_t* __restrict__ w1t,
    bf16_t* __restrict__ w3pt, float* __restrict__ c2) {
  __shared__ float lds[64][65];
  const int b = blockIdx.x;
  const int t = threadIdx.x;
  if (b == 512) {
    float s = 64.f * bias2[t];
#pragma unroll 8
    for (int r = 0; r < 64; ++r) s += bias1[r] * w2s[r * 256 + t];
    c2[t] = s;
    return;
  }
  if (b < 256) {
    const int k0 = (b >> 2) * 64;
    const int mt = (b & 3) * 64;
#pragma unroll
    for (int it = 0; it < 16; ++it) {
      int idx = t + it * 256;
      int kl = idx >> 6, ml = idx & 63;
      int k = k0 + kl;
      lds[kl][ml] = w1[(size_t)k * 256 + mt + ml] * w2s[(k & 63) * 256 + mt + ml];
    }
    __syncthreads();
#pragma unroll
    for (int it = 0; it < 16; ++it) {
      int idx = t + it * 256;
      int ml = idx >> 6, kl = idx & 63;
      w1t[(size_t)(mt + ml) * 4096 + k0 + kl] = (bf16_t)lds[kl][ml];
    }
    return;
  }
  const int b2 = b - 256;
  const int r = b2 & 63;
  const int mt = (b2 >> 6) * 64;
#pragma unroll
  for (int it = 0; it < 16; ++it) {
    int idx = t + it * 256;
    int ml = idx >> 6, o = idx & 63;
    lds[ml][o] = w3[(size_t)(mt + ml) * 4096 + r * 64 + o];
  }
  __syncthreads();
#pragma unroll
  for (int it = 0; it < 16; ++it) {
    int idx = t + it * 256;
    int o = idx >> 6, ml = idx & 63;
    w3pt[(size_t)(o * 64 + r) * 256 + mt + ml] = (bf16_t)lds[ml][o];
  }
}

// ---------------- GEMM1 v10: max-MLP, barrier-free ----------------
// S4[t, ks*256+n] = sum_{k in slice ks (256 wide)} bf16(X[t,k]) * W1T[n,k]
// 2048 blocks x 4 waves = 8192 independent waves; wave = 16 rows x 256 cols x 256 K.
// XCD x owns rowgrps x*64..x*64+63 (rows x*1024..+1023, matches reduce/gemm2).
// Per step (BK=32): 18 loads issued up front (X prefetched 1 step ahead, W1T L2-hit),
// then 16 independent MFMAs -> ONE wait point per step. 8 steps. No __syncthreads.
__global__ __launch_bounds__(256, 4) void gemm1_k(
    const float* __restrict__ X, const bf16_t* __restrict__ W1T,
    bf16_t* __restrict__ S4) {
  __shared__ __align__(16) bf16_t eps[4][16 * 264];  // wave-private, padded stride
  const int tid = threadIdx.x;
  const int lane = tid & 63;
  const int wv = tid >> 6;
  const int bid = (int)blockIdx.x;
  const int xcd = bid & 7;
  const int u = bid >> 3;                  // 0..255
  const int rowgrp = xcd * 64 + (u >> 2);  // 0..511
  const int ks = (u & 3) * 4 + wv;         // 0..15
  const size_t m0 = (size_t)rowgrp * 16;
  const int kbase = ks * 256;
  const int lr = lane & 15;                // token-row / n-row within 16
  const int lk8 = (lane >> 4) * 8;         // k sub-offset (8 elements)

  f32x4 acc[16];
#pragma unroll
  for (int j = 0; j < 16; ++j) acc[j] = (f32x4){0.f, 0.f, 0.f, 0.f};

  const float* xp = X + (m0 + lr) * 4096 + (size_t)(kbase + lk8);
  const bf16_t* bp = W1T + (size_t)lr * 4096 + (size_t)(kbase + lk8);

  float4 u0 = *(const float4*)(xp);
  float4 v0 = *(const float4*)(xp + 4);

#pragma unroll
  for (int t = 0; t < 8; ++t) {
    float4 un, vn;
    if (t < 7) {  // compile-time in unrolled copies; avoids OOB on last step
      un = *(const float4*)(xp + (t + 1) * 32);
      vn = *(const float4*)(xp + (t + 1) * 32 + 4);
    }
    // W1T fragments: two groups of 8 (caps register pressure)
    bf16x8 b[8];
#pragma unroll
    for (int nf = 0; nf < 8; ++nf)
      b[nf] = *(const bf16x8*)(bp + (size_t)nf * 16 * 4096 + t * 32);
    bf16x8 a;
    a[0] = (bf16_t)u0.x; a[1] = (bf16_t)u0.y; a[2] = (bf16_t)u0.z; a[3] = (bf16_t)u0.w;
    a[4] = (bf16_t)v0.x; a[5] = (bf16_t)v0.y; a[6] = (bf16_t)v0.z; a[7] = (bf16_t)v0.w;
#pragma unroll
    for (int nf = 0; nf < 8; ++nf)
      acc[nf] = __builtin_amdgcn_mfma_f32_16x16x32_bf16(a, b[nf], acc[nf], 0, 0, 0);
#pragma unroll
    for (int nf = 0; nf < 8; ++nf)
      b[nf] = *(const bf16x8*)(bp + (size_t)(8 + nf) * 16 * 4096 + t * 32);
#pragma unroll
    for (int nf = 0; nf < 8; ++nf)
      acc[8 + nf] = __builtin_amdgcn_mfma_f32_16x16x32_bf16(a, b[nf], acc[8 + nf], 0, 0, 0);
    if (t < 7) { u0 = un; v0 = vn; }
  }

  // epilogue: wave-private LDS transpose -> coalesced bf16x8 stores
  bf16_t* ep = &eps[wv][0];
#pragma unroll
  for (int nf = 0; nf < 16; ++nf)
#pragma unroll
    for (int q = 0; q < 4; ++q) {
      int row = (lane >> 4) * 4 + q;       // 0..15
      int col = nf * 16 + lr;              // 0..255
      ep[row * 264 + col] = (bf16_t)acc[nf][q];
    }
  LGKM0;  // wave-private buffer: own writes complete before own reads
  __builtin_amdgcn_sched_barrier(0);
#pragma unroll
  for (int it = 0; it < 8; ++it) {
    int chunk = it * 64 + lane;            // 0..511
    int row = chunk >> 5;                  // 0..15
    int c8 = (chunk & 31) << 3;            // 0..248
    bf16x8 v = *(const bf16x8*)(ep + row * 264 + c8);
    *(bf16x8*)(S4 + (m0 + row) * 4096 + (size_t)(kbase + c8)) = v;
  }
}

// ---------------- reduce: S[t,m] = bf16( sum_{h=0..15} S4[t, h*256+m] + c2[m] )
// grid 1024; XCD-aligned: x = bid&7 handles rows x*1024 + (bid>>3)*8 .. +7
__global__ __launch_bounds__(256) void reduce_k(
    const bf16_t* __restrict__ S4, const float* __restrict__ c2,
    bf16_t* __restrict__ S) {
  const int bid = (int)blockIdx.x;
  const int row = (bid & 7) * 1024 + (bid >> 3) * 8 + (threadIdx.x >> 5);
  const int c8 = (threadIdx.x & 31) << 3;
  float s[8];
  float4 ca = *(const float4*)(c2 + c8);
  float4 cb = *(const float4*)(c2 + c8 + 4);
  s[0] = ca.x; s[1] = ca.y; s[2] = ca.z; s[3] = ca.w;
  s[4] = cb.x; s[5] = cb.y; s[6] = cb.z; s[7] = cb.w;
#pragma unroll
  for (int h = 0; h < 16; ++h) {
    bf16x8 v = *(const bf16x8*)(S4 + (size_t)row * 4096 + h * 256 + c8);
#pragma unroll
    for (int j = 0; j < 8; ++j) s[j] += (float)v[j];
  }
  bf16x8 o;
#pragma unroll
  for (int j = 0; j < 8; ++j) o[j] = (bf16_t)s[j];
  *(bf16x8*)(S + (size_t)row * 256 + c8) = o;
}

// ---------------- GEMM2 (unchanged): OUT[t,j] = sum_m S[t,m]*W3pT[j,m] + bias3[j&63]
__global__ __launch_bounds__(512, 2) void gemm2_k(
    const bf16_t* __restrict__ S, const bf16_t* __restrict__ W3pT,
    const float* __restrict__ bias3, float* __restrict__ OUT) {
  __shared__ __align__(16) bf16_t lA[2][128 * 64];
  __shared__ __align__(16) bf16_t lB[2][256 * 64];
  const int tid = threadIdx.x;
  const int lane = tid & 63;
  const int wv = tid >> 6;
  const int bid = (int)blockIdx.x;
  const int xcd = bid & 7;
  const int rest = bid >> 3;
  const int mt = xcd * 8 + (rest >> 4);
  const int nt = rest & 15;
  const size_t m0 = (size_t)mt * 128;
  const int n0 = nt * 256;
  const int wm = wv >> 2, wn = wv & 3;

  f32x4 acc[4][4];
#pragma unroll
  for (int i = 0; i < 4; ++i)
#pragma unroll
    for (int j = 0; j < 4; ++j) acc[i][j] = (f32x4){0.f, 0.f, 0.f, 0.f};

  auto stage = [&](int buf, int kt) {
#pragma unroll
    for (int i = 0; i < 2; ++i) {
      int row = wv * 16 + i * 8 + (lane >> 3);
      int srckb = ((lane & 7) * 16) ^ ((row & 7) << 4);
      const char* srcA = (const char*)S + (m0 + row) * 512 + (size_t)(kt * 128) + srckb;
      char* dstA = (char*)(&lA[buf][0]) + (wv * 16 + i * 8) * 128;
      gload_lds16(srcA, dstA);
    }
#pragma unroll
    for (int i = 0; i < 4; ++i) {
      int row = wv * 32 + i * 8 + (lane >> 3);
      int srckb = ((lane & 7) * 16) ^ ((row & 7) << 4);
      const char* srcB = (const char*)W3pT + (size_t)(n0 + row) * 512 + (size_t)(kt * 128) + srckb;
      char* dstB = (char*)(&lB[buf][0]) + (wv * 32 + i * 8) * 128;
      gload_lds16(srcB, dstB);
    }
  };
  auto compute = [&](int buf) {
#pragma unroll
    for (int kk = 0; kk < 2; ++kk) {
      const int kb = kk * 64 + ((lane >> 4) * 16);
      bf16x8 af[4], bfr[4];
#pragma unroll
      for (int mf = 0; mf < 4; ++mf) {
        int row = wm * 64 + mf * 16 + (lane & 15);
        int off = row * 128 + (kb ^ ((row & 7) << 4));
        af[mf] = *(const bf16x8*)((const char*)(&lA[buf][0]) + off);
      }
#pragma unroll
      for (int nf = 0; nf < 4; ++nf) {
        int row = wn * 64 + nf * 16 + (lane & 15);
        int off = row * 128 + (kb ^ ((row & 7) << 4));
        bfr[nf] = *(const bf16x8*)((const char*)(&lB[buf][0]) + off);
      }
#pragma unroll
      for (int mf = 0; mf < 4; ++mf)
#pragma unroll
        for (int nf = 0; nf < 4; ++nf)
          acc[mf][nf] = __builtin_amdgcn_mfma_f32_16x16x32_bf16(af[mf], bfr[nf], acc[mf][nf], 0, 0, 0);
    }
  };

  stage(0, 0);
  CFENCE;
  stage(1, 1);
  CFENCE;
  VMW(6);
  RAWBAR;
  compute(0);
  RAWBAR;
  stage(0, 2);
  CFENCE;
  VMW(6);
  RAWBAR;
  compute(1);
  RAWBAR;
  stage(1, 3);
  CFENCE;
  VMW(6);
  RAWBAR;
  compute(0);
  RAWBAR;
  VMW(0);
  RAWBAR;
  compute(1);

#pragma unroll
  for (int nf = 0; nf < 4; ++nf) {
    int jcol = wn * 64 + nf * 16 + (lane & 15);
    float b3 = bias3[jcol & 63];
    int j = n0 + jcol;
#pragma unroll
    for (int mf = 0; mf < 4; ++mf) {
#pragma unroll
      for (int q = 0; q < 4; ++q) {
        size_t row = m0 + (size_t)(wm * 64 + mf * 16 + (lane >> 4) * 4 + q);
        OUT[row * 4096 + j] = acc[mf][nf][q] + b3;
      }
    }
  }
}

extern "C" void kernel_launch(void* const* d_in, const int* in_sizes, int n_in,
                              void* d_out, int out_size, void* d_ws, size_t ws_size,
                              hipStream_t stream) {
  (void)in_sizes; (void)n_in; (void)out_size; (void)ws_size;
  const float* x  = (const float*)d_in[0];
  const float* w1 = (const float*)d_in[1];
  const float* w2 = (const float*)d_in[2];
  const float* w3 = (const float*)d_in[3];
  const float* b1 = (const float*)d_in[4];
  const float* b2 = (const float*)d_in[5];
  const float* b3 = (const float*)d_in[6];
  float* out = (float*)d_out;
  char* ws = (char*)d_ws;

  // workspace layout
  float*  w2s  = (float*)(ws + 0);                   // 64 KB
  float*  c2   = (float*)(ws + 65536);               // 1 KB (+pad)
  bf16_t* w1t  = (bf16_t*)(ws + 69632);              // 2 MB  [256][4096] bf16
  bf16_t* w3pt = (bf16_t*)(ws + 69632 + 2097152);    // 2 MB  [4096][256] bf16
  bf16_t* S4   = (bf16_t*)(ws + 69632 + 4194304);    // 64 MB [8192][4096] bf16
  bf16_t* S    = (bf16_t*)(ws + 69632 + 4194304 + 67108864);  // 4 MB [8192][256] bf16

  w2s_k<<<64, 256, 0, stream>>>(w2, w2s);
  prep_k<<<513, 256, 0, stream>>>(w1, w3, w2s, b1, b2, w1t, w3pt, c2);
  gemm1_k<<<2048, 256, 0, stream>>>(x, w1t, S4);
  reduce_k<<<1024, 256, 0, stream>>>(S4, c2, S);
  gemm2_k<<<1024, 512, 0, stream>>>(S, w3pt, b3, out);
}